// Round 4
// baseline (3384.461 us; speedup 1.0000x reference)
//
#include <hip/hip_runtime.h>
#include <hip/hip_bf16.h>

#define UNIT 20
#define HID 36
#define G4 144      // 4*HID
#define INW 80      // 4*UNIT
#define NCLS 3
#define TT 40960
#define SS 2048     // TT/UNIT
#define BB 512
#define NPROD 256   // producer blocks (2 batches each)
#define NCONS 128   // consumer blocks (4 waves = 4 batches each)
#define CHK 128     // steps per chunk
#define NCHK (SS/CHK)

__device__ __forceinline__ float exp2_hw(float x){ float r; asm("v_exp_f32 %0, %1" : "=v"(r) : "v"(x)); return r; }
__device__ __forceinline__ float rcp_hw(float x){ float r; asm("v_rcp_f32 %0, %1" : "=v"(r) : "v"(x)); return r; }
__device__ __forceinline__ float sigm_hw(float x){ return rcp_hw(1.f + exp2_hw(-1.4426950408889634f * x)); }
__device__ __forceinline__ float tanh_hw(float x){ return 1.f - 2.f * rcp_hw(1.f + exp2_hw(2.8853900817779268f * x)); }
__device__ __forceinline__ float rl(float v, int l){
    return __uint_as_float(__builtin_amdgcn_readlane(__float_as_uint(v), l));
}

__global__ void init_flags(int* f){ f[threadIdx.x] = 0; }

// ------------- persistent producer/consumer kernel -------------
__global__ __launch_bounds__(256)
void lstm_pc(const float* __restrict__ x, const float* __restrict__ h0,
             const float* __restrict__ c0, const float* __restrict__ W_ih,
             const float* __restrict__ W_hh, const float* __restrict__ b_ih,
             const float* __restrict__ b_hh, const float* __restrict__ fc1_w,
             const float* __restrict__ fc1_b, const float* __restrict__ fc2_w,
             const float* __restrict__ fc2_b, float* __restrict__ out,
             int* __restrict__ flags, float* __restrict__ xw)
{
    const int tid = threadIdx.x;

    if (blockIdx.x < NPROD) {
        // ================= producer =================
        __shared__ __align__(16) float xin[16][INW];
        const int p = blockIdx.x;

        float wih[INW]; float bias = 0.f;
        if (tid < G4) {
            const float4* wr = (const float4*)(W_ih + (size_t)tid * INW);
            #pragma unroll
            for (int q = 0; q < INW/4; ++q) {
                float4 v = wr[q];
                wih[4*q+0]=v.x; wih[4*q+1]=v.y; wih[4*q+2]=v.z; wih[4*q+3]=v.w;
            }
            bias = b_ih[tid] + b_hh[tid];
        }

        for (int k = 0; k < NCHK; ++k) {
            for (int half = 0; half < 2; ++half) {
                const int b = 2*p + half;
                const float* xb = x + (size_t)b * 4 * TT;
                for (int sub = 0; sub < CHK/16; ++sub) {
                    const int sg = k*CHK + sub*16;
                    __syncthreads();                 // xin reuse guard
                    for (int j = tid; j < 320; j += 256) {
                        int c = j / 80, q = j - c*80;
                        float4 v = ((const float4*)(xb + (size_t)c*TT + (size_t)sg*UNIT))[q];
                        int e = q*4; int sl = e / UNIT, u = e - sl*UNIT;
                        *(float4*)&xin[sl][c*UNIT + u] = v;
                    }
                    __syncthreads();
                    if (tid < G4) {
                        for (int s = 0; s < 16; ++s) {
                            const float4* xv = (const float4*)xin[s];
                            float a0 = bias, a1 = 0.f, a2 = 0.f, a3 = 0.f;
                            #pragma unroll
                            for (int q = 0; q < INW/4; ++q) {
                                float4 v = xv[q];
                                a0 += v.x * wih[4*q+0];
                                a1 += v.y * wih[4*q+1];
                                a2 += v.z * wih[4*q+2];
                                a3 += v.w * wih[4*q+3];
                            }
                            xw[((size_t)(sg + s) * BB + b) * G4 + tid] = (a0+a1)+(a2+a3);
                        }
                    }
                }
            }
            // publish chunk k: every thread drains+fences its own stores, then one count
            __threadfence();
            __syncthreads();
            if (tid == 0)
                __hip_atomic_fetch_add(&flags[k], 1, __ATOMIC_RELEASE, __HIP_MEMORY_SCOPE_AGENT);
        }
    } else {
        // ================= consumer =================
        const int wid  = tid >> 6;
        const int lane = tid & 63;
        const int b    = (blockIdx.x - NPROD) * 4 + wid;
        const int jj   = (lane < HID) ? lane : 0;

        float wreg[G4];
        #pragma unroll
        for (int g = 0; g < 4; ++g) {
            const float* wr = W_hh + (size_t)(g*HID + jj) * HID;
            #pragma unroll
            for (int q = 0; q < HID; ++q) wreg[g*HID + q] = wr[q];
        }

        float hval = h0[b*HID + jj];
        float cval = c0[b*HID + jj];
        float hs[HID];
        #pragma unroll
        for (int q = 0; q < HID; ++q) hs[q] = rl(hval, q);

        const float*  xp     = xw + (size_t)b * G4 + jj;
        const size_t  STRIDE = (size_t)BB * G4;

        float qa[8][4], qb[8][4];

#define LOADBANK(dst, loc) { \
    _Pragma("unroll") for (int u = 0; u < 8; ++u) { \
        int ls = (loc) + u; \
        const float* pp = xp + (basea + (size_t)((ls < CHK) ? ls : 0)) * STRIDE; \
        _Pragma("unroll") for (int g = 0; g < 4; ++g) dst[u][g] = pp[g*HID]; \
    } }

#define DOSTEP(bk, u) { \
    float ai = bk[u][0], af = bk[u][1], ag = bk[u][2], ao = bk[u][3]; \
    _Pragma("unroll") for (int q = 0; q < HID; ++q) { \
        ai += hs[q] * wreg[q]; \
        af += hs[q] * wreg[HID   + q]; \
        ag += hs[q] * wreg[2*HID + q]; \
        ao += hs[q] * wreg[3*HID + q]; \
    } \
    float gi = sigm_hw(ai), gf = sigm_hw(af), gg = tanh_hw(ag), go = sigm_hw(ao); \
    cval = gf * cval + gi * gg; \
    hval = go * tanh_hw(cval); \
    _Pragma("unroll") for (int q = 0; q < HID; ++q) hs[q] = rl(hval, q); }

        for (int k = 0; k < NCHK; ++k) {
            while (__hip_atomic_load(&flags[k], __ATOMIC_ACQUIRE, __HIP_MEMORY_SCOPE_AGENT) < NPROD)
                __builtin_amdgcn_s_sleep(2);
            const size_t basea = (size_t)k * CHK;
            LOADBANK(qa, 0);
            for (int s8 = 0; s8 < CHK; s8 += 16) {
                LOADBANK(qb, s8 + 8);
                DOSTEP(qa,0) DOSTEP(qa,1) DOSTEP(qa,2) DOSTEP(qa,3)
                DOSTEP(qa,4) DOSTEP(qa,5) DOSTEP(qa,6) DOSTEP(qa,7)
                LOADBANK(qa, s8 + 16);
                DOSTEP(qb,0) DOSTEP(qb,1) DOSTEP(qb,2) DOSTEP(qb,3)
                DOSTEP(qb,4) DOSTEP(qb,5) DOSTEP(qb,6) DOSTEP(qb,7)
            }
        }
#undef LOADBANK
#undef DOSTEP

        // classifier head, in-wave (hs holds final h, uniform)
        float a1 = 0.f;
        if (lane < 16) {
            a1 = fc1_b[lane];
            #pragma unroll
            for (int q = 0; q < HID; ++q) a1 += hs[q] * fc1_w[lane*HID + q];
            a1 = fmaxf(a1, 0.f);
        }
        float f1[16];
        #pragma unroll
        for (int q = 0; q < 16; ++q) f1[q] = rl(a1, q);
        if (lane < NCLS) {
            float a2 = fc2_b[lane];
            #pragma unroll
            for (int q = 0; q < 16; ++q) a2 += f1[q] * fc2_w[lane*16 + q];
            out[b*NCLS + lane] = a2;
        }
    }
}

// ================= fallback path (proven R3 kernels) =================
__global__ __launch_bounds__(192)
void lstm_proj(const float* __restrict__ x, const float* __restrict__ W_ih,
               const float* __restrict__ b_ih, const float* __restrict__ b_hh,
               float* __restrict__ xw, int s0, int cnt, int nseq)
{
    const int bid = blockIdx.x;
    const int r   = bid % nseq;
    const int b   = bid / nseq;
    const int tid = threadIdx.x;
    const int base_local = r * 128;
    const int mysteps = min(128, cnt - base_local);

    __shared__ __align__(16) float xin[16][INW];

    float wih[INW]; float bias = 0.f;
    if (tid < G4) {
        const float4* wr = (const float4*)(W_ih + (size_t)tid * INW);
        #pragma unroll
        for (int q = 0; q < INW/4; ++q) {
            float4 v = wr[q];
            wih[4*q+0]=v.x; wih[4*q+1]=v.y; wih[4*q+2]=v.z; wih[4*q+3]=v.w;
        }
        bias = b_ih[tid] + b_hh[tid];
    }
    const float* xb = x + (size_t)b * 4 * TT;

    for (int sub = 0; sub < mysteps; sub += 16) {
        const int sg = s0 + base_local + sub;
        __syncthreads();
        for (int j = tid; j < 320; j += 192) {
            int c = j / 80, q = j - c*80;
            float4 v = ((const float4*)(xb + (size_t)c*TT + (size_t)sg*UNIT))[q];
            int e = q*4; int sl = e / UNIT, u = e - sl*UNIT;
            *(float4*)&xin[sl][c*UNIT + u] = v;
        }
        __syncthreads();
        if (tid < G4) {
            for (int s = 0; s < 16; ++s) {
                const float4* xv = (const float4*)xin[s];
                float a0 = bias, a1 = 0.f, a2 = 0.f, a3 = 0.f;
                #pragma unroll
                for (int q = 0; q < INW/4; ++q) {
                    float4 v = xv[q];
                    a0 += v.x * wih[4*q+0];
                    a1 += v.y * wih[4*q+1];
                    a2 += v.z * wih[4*q+2];
                    a3 += v.w * wih[4*q+3];
                }
                xw[((size_t)(base_local + sub + s) * BB + b) * G4 + tid] = (a0+a1)+(a2+a3);
            }
        }
    }
}

__global__ __launch_bounds__(256)
void lstm_recur(const float* __restrict__ xw, const float* __restrict__ h0,
                const float* __restrict__ c0, const float* __restrict__ W_hh,
                const float* __restrict__ fc1_w, const float* __restrict__ fc1_b,
                const float* __restrict__ fc2_w, const float* __restrict__ fc2_b,
                float* __restrict__ state, float* __restrict__ out, int s0, int cnt)
{
    const int wid  = threadIdx.x >> 6;
    const int lane = threadIdx.x & 63;
    const int b    = blockIdx.x * 4 + wid;
    const int jj   = (lane < HID) ? lane : 0;

    float wreg[G4];
    #pragma unroll
    for (int g = 0; g < 4; ++g) {
        const float* wr = W_hh + (size_t)(g*HID + jj) * HID;
        #pragma unroll
        for (int q = 0; q < HID; ++q) wreg[g*HID + q] = wr[q];
    }

    float hval, cval;
    if (s0 == 0) { hval = h0[b*HID + jj];    cval = c0[b*HID + jj]; }
    else         { hval = state[b*HID + jj]; cval = state[BB*HID + b*HID + jj]; }

    float hs[HID];
    #pragma unroll
    for (int q = 0; q < HID; ++q) hs[q] = rl(hval, q);

    const float*  xp     = xw + (size_t)b * G4 + jj;
    const size_t  STRIDE = (size_t)BB * G4;

    float qa[8][4], qb[8][4];

#define LOADBANK(dst, base) { \
    _Pragma("unroll") for (int u = 0; u < 8; ++u) { \
        int ss = (base) + u; \
        const float* p = xp + (size_t)((ss < cnt) ? ss : 0) * STRIDE; \
        _Pragma("unroll") for (int g = 0; g < 4; ++g) dst[u][g] = p[g*HID]; \
    } }

#define DOSTEP(bk, u) { \
    float ai = bk[u][0], af = bk[u][1], ag = bk[u][2], ao = bk[u][3]; \
    _Pragma("unroll") for (int q = 0; q < HID; ++q) { \
        ai += hs[q] * wreg[q]; \
        af += hs[q] * wreg[HID   + q]; \
        ag += hs[q] * wreg[2*HID + q]; \
        ao += hs[q] * wreg[3*HID + q]; \
    } \
    float gi = sigm_hw(ai), gf = sigm_hw(af), gg = tanh_hw(ag), go = sigm_hw(ao); \
    cval = gf * cval + gi * gg; \
    hval = go * tanh_hw(cval); \
    _Pragma("unroll") for (int q = 0; q < HID; ++q) hs[q] = rl(hval, q); }

    LOADBANK(qa, 0);
    for (int s8 = 0; s8 < cnt; s8 += 16) {
        LOADBANK(qb, s8 + 8);
        DOSTEP(qa,0) DOSTEP(qa,1) DOSTEP(qa,2) DOSTEP(qa,3)
        DOSTEP(qa,4) DOSTEP(qa,5) DOSTEP(qa,6) DOSTEP(qa,7)
        LOADBANK(qa, s8 + 16);
        DOSTEP(qb,0) DOSTEP(qb,1) DOSTEP(qb,2) DOSTEP(qb,3)
        DOSTEP(qb,4) DOSTEP(qb,5) DOSTEP(qb,6) DOSTEP(qb,7)
    }
#undef LOADBANK
#undef DOSTEP

    if (s0 + cnt == SS) {
        float a1 = 0.f;
        if (lane < 16) {
            a1 = fc1_b[lane];
            #pragma unroll
            for (int k = 0; k < HID; ++k) a1 += hs[k] * fc1_w[lane*HID + k];
            a1 = fmaxf(a1, 0.f);
        }
        float f1[16];
        #pragma unroll
        for (int k = 0; k < 16; ++k) f1[k] = rl(a1, k);
        if (lane < NCLS) {
            float a2 = fc2_b[lane];
            #pragma unroll
            for (int k = 0; k < 16; ++k) a2 += f1[k] * fc2_w[lane*16 + k];
            out[b*NCLS + lane] = a2;
        }
    } else {
        if (lane < HID) {
            state[b*HID + lane]          = hval;
            state[BB*HID + b*HID + lane] = cval;
        }
    }
}

__global__ __launch_bounds__(192)
void lstm_fused(const float* __restrict__ x, const float* __restrict__ h0,
                const float* __restrict__ c0, const float* __restrict__ W_ih,
                const float* __restrict__ W_hh, const float* __restrict__ b_ih,
                const float* __restrict__ b_hh, const float* __restrict__ fc1_w,
                const float* __restrict__ fc1_b, const float* __restrict__ fc2_w,
                const float* __restrict__ fc2_b, float* __restrict__ out)
{
    const int b = blockIdx.x;
    const int t = threadIdx.x;
    __shared__ __align__(16) float xin[16][INW];
    __shared__ __align__(16) float xwl[16][G4];
    __shared__ __align__(16) float h_s[HID];
    __shared__ __align__(16) float g_s[G4];
    float wih[INW]; float whh[HID];
    float bias = 0.f, K = 0.f, Aa = 0.f, Bb = 0.f;
    if (t < G4) {
        const float4* wr = (const float4*)(W_ih + t * INW);
        #pragma unroll
        for (int i = 0; i < INW/4; ++i) { float4 v = wr[i]; wih[4*i]=v.x; wih[4*i+1]=v.y; wih[4*i+2]=v.z; wih[4*i+3]=v.w; }
        const float4* hr = (const float4*)(W_hh + t * HID);
        #pragma unroll
        for (int j = 0; j < HID/4; ++j) { float4 v = hr[j]; whh[4*j]=v.x; whh[4*j+1]=v.y; whh[4*j+2]=v.z; whh[4*j+3]=v.w; }
        bias = b_ih[t] + b_hh[t];
        const bool tnh = (t >= 2*HID && t < 3*HID);
        K  = tnh ?  2.8853900817779268f : -1.4426950408889634f;
        Aa = tnh ?  1.f : 0.f;
        Bb = tnh ? -2.f : 1.f;
    }
    float c = 0.f;
    if (t < HID) { c = c0[b*HID + t]; h_s[t] = h0[b*HID + t]; }
    __syncthreads();
    const float* xb = x + (size_t)b * 4 * TT;
    for (int ck = 0; ck < SS/16; ++ck) {
        const int base = ck * 16 * UNIT;
        for (int j = t; j < 4*16*UNIT; j += 192) {
            int chn = j / (16*UNIT); int r = j - chn*(16*UNIT);
            xin[r/UNIT][chn*UNIT + (r%UNIT)] = xb[chn*TT + base + r];
        }
        __syncthreads();
        if (t < G4) {
            for (int s = 0; s < 16; ++s) {
                const float4* xv = (const float4*)xin[s];
                float a0 = bias, a1 = 0.f, a2 = 0.f, a3 = 0.f;
                #pragma unroll
                for (int i = 0; i < INW/4; ++i) {
                    float4 v = xv[i];
                    a0 += v.x*wih[4*i]; a1 += v.y*wih[4*i+1]; a2 += v.z*wih[4*i+2]; a3 += v.w*wih[4*i+3];
                }
                xwl[s][t] = (a0+a1)+(a2+a3);
            }
        }
        __syncthreads();
        for (int s = 0; s < 16; ++s) {
            if (t < G4) {
                const float4* hv = (const float4*)h_s;
                float a0 = xwl[s][t], a1 = 0.f, a2 = 0.f, a3 = 0.f;
                #pragma unroll
                for (int j = 0; j < HID/4; ++j) {
                    float4 v = hv[j];
                    a0 += v.x*whh[4*j]; a1 += v.y*whh[4*j+1]; a2 += v.z*whh[4*j+2]; a3 += v.w*whh[4*j+3];
                }
                float acc = (a0+a1)+(a2+a3);
                g_s[t] = Aa + Bb * rcp_hw(1.f + exp2_hw(K * acc));
            }
            __syncthreads();
            if (t < HID) {
                float ig=g_s[t], fg=g_s[HID+t], gg=g_s[2*HID+t], og=g_s[3*HID+t];
                c = fg*c + ig*gg;
                h_s[t] = og * tanh_hw(c);
            }
            __syncthreads();
        }
    }
    if (t < 16) {
        float a = fc1_b[t];
        #pragma unroll
        for (int j = 0; j < HID; ++j) a += h_s[j]*fc1_w[t*HID+j];
        g_s[t] = fmaxf(a, 0.f);
    }
    __syncthreads();
    if (t < NCLS) {
        float a = fc2_b[t];
        #pragma unroll
        for (int j = 0; j < 16; ++j) a += g_s[j]*fc2_w[t*16+j];
        out[b*NCLS + t] = a;
    }
}

extern "C" void kernel_launch(void* const* d_in, const int* in_sizes, int n_in,
                              void* d_out, int out_size, void* d_ws, size_t ws_size,
                              hipStream_t stream) {
    const float* x     = (const float*)d_in[0];
    const float* h0    = (const float*)d_in[1];
    const float* c0    = (const float*)d_in[2];
    const float* W_ih  = (const float*)d_in[3];
    const float* W_hh  = (const float*)d_in[4];
    const float* b_ih  = (const float*)d_in[5];
    const float* b_hh  = (const float*)d_in[6];
    const float* fc1_w = (const float*)d_in[7];
    const float* fc1_b = (const float*)d_in[8];
    const float* fc2_w = (const float*)d_in[9];
    const float* fc2_b = (const float*)d_in[10];
    float* out = (float*)d_out;

    const size_t need = 4ull * (64 + (size_t)SS * BB * G4);   // flags + full xw
    if (ws_size >= need) {
        int*   flags = (int*)d_ws;
        float* xwbuf = (float*)d_ws + 64;
        init_flags<<<1, 64, 0, stream>>>(flags);
        lstm_pc<<<NPROD + NCONS, 256, 0, stream>>>(x, h0, c0, W_ih, W_hh, b_ih, b_hh,
                                                   fc1_w, fc1_b, fc2_w, fc2_b, out,
                                                   flags, xwbuf);
        return;
    }

    // ---- fallback: proven R3 chunked path ----
    const size_t state_floats = (size_t)BB * HID * 2;
    long cap = (long)(ws_size / 4) - (long)state_floats;
    long sc  = (cap > 0) ? cap / ((long)BB * G4) : 0;
    int  SC  = (int)((sc > SS) ? SS : sc) & ~15;

    if (SC < 16) {
        lstm_fused<<<BB, 192, 0, stream>>>(x, h0, c0, W_ih, W_hh, b_ih, b_hh,
                                           fc1_w, fc1_b, fc2_w, fc2_b, out);
        return;
    }

    float* state = (float*)d_ws;
    float* xwbuf = state + state_floats;

    for (int s0 = 0; s0 < SS; s0 += SC) {
        int cnt = SS - s0; if (cnt > SC) cnt = SC;
        int nseq = (cnt + 127) / 128;
        lstm_proj<<<BB * nseq, 192, 0, stream>>>(x, W_ih, b_ih, b_hh, xwbuf, s0, cnt, nseq);
        lstm_recur<<<BB / 4, 256, 0, stream>>>(xwbuf, h0, c0, W_hh,
                                               fc1_w, fc1_b, fc2_w, fc2_b,
                                               state, out, s0, cnt);
    }
}